// Round 4
// baseline (807.711 us; speedup 1.0000x reference)
//
#include <hip/hip_runtime.h>

#define S_LEN 2048
#define D_DIM 128
#define BM 128
#define BK 64
#define NIT (S_LEN / BK)
#define LQ 136   // Q/K row stride (bf16 elems), 272B rows, 16B-aligned
#define LV 72    // Vt row stride (bf16 elems), 144B rows, 16B-aligned
#define KS_E (BK * LQ)          // 8704 elems
#define VT_E (D_DIM * LV)       // 9216 elems
#define BUF_E (KS_E + VT_E)     // 17920 elems = 35840 B; x2 = 71680 B -> 2 blocks/CU

typedef __attribute__((ext_vector_type(8))) short bf16x8;  // 8 bf16 (4 VGPRs)
typedef __attribute__((ext_vector_type(4))) float f32x4;   // MFMA accumulator
typedef __attribute__((ext_vector_type(4))) int i32x4;

// fp32 -> bf16 pair pack: round-half-away (u+0x8000) then byte-perm.
__device__ __forceinline__ unsigned rnd16(float x) {
    union { float f; unsigned u; } c; c.f = x;
    return c.u + 0x8000u;
}
__device__ __forceinline__ unsigned pack2(float lo, float hi) {
    return __builtin_amdgcn_perm(rnd16(hi), rnd16(lo), 0x07060302);
}

// One block: 128 Q-rows of one (b,h); 32 iters over t-chunks of 64.
// Q held in registers (staged once via LDS overlay). Ks/Vt double-buffered:
// K(i+1)/V(i+1)/mask(i+1) prefetched while gemms run on buffer i; ONE
// barrier per iter. P redistributed S->O layout via ds_bpermute (no LDS).
__global__ __launch_bounds__(256, 2)
void fused_qkmv(const float* __restrict__ q, const float* __restrict__ k,
                const float* __restrict__ v, const float* __restrict__ mask,
                float* __restrict__ out) {
    __shared__ __align__(16) unsigned short smem[2 * BUF_E];
    // buffer b: Ks at smem + b*BUF_E, Vt at smem + b*BUF_E + KS_E
    unsigned short* const Qst = smem;  // prologue overlay of buf0

    const int tid  = threadIdx.x;
    const int lane = tid & 63;
    const int w    = tid >> 6;   // wave 0..3: s-range 32w..32w+31
    const int l15  = lane & 15;
    const int qd   = lane >> 4;

    const int bh = blockIdx.x >> 4;
    const int s0 = (blockIdx.x & 15) * BM;

    const float* qp = q + (size_t)bh * S_LEN * D_DIM;
    const float* kp = k + (size_t)bh * S_LEN * D_DIM;
    const float* vp = v + (size_t)bh * S_LEN * D_DIM;
    const float* mp = mask + (size_t)bh * S_LEN * S_LEN;
    float*       op = out + (size_t)bh * S_LEN * D_DIM;

    // staging index maps
    const int rr = tid >> 5, dd = (tid & 31) * 4;        // K/Q rows: half-wave = one row
    const int tg = (tid & 15) * 4, dg = (tid >> 4) * 8;  // V transpose micro-tile

    // ---- prologue: issue K0/V0/mask0 loads, then stage Q ----
    float4 kf[8];
#pragma unroll
    for (int sw = 0; sw < 8; ++sw)
        kf[sw] = *(const float4*)(kp + (size_t)(sw * 8 + rr) * D_DIM + dd);
    float4 va[4], vb[4];
#pragma unroll
    for (int r = 0; r < 4; ++r) {
        va[r] = *(const float4*)(vp + (size_t)(tg + r) * D_DIM + dg);
        vb[r] = *(const float4*)(vp + (size_t)(tg + r) * D_DIM + dg + 4);
    }
    float4 mreg[4][2];  // [ti][sj] for current iter
    {
        const float* mb = mp + (size_t)(s0 + 32 * w + l15) * S_LEN + 4 * qd;
#pragma unroll
        for (int ti = 0; ti < 4; ++ti)
#pragma unroll
            for (int sj = 0; sj < 2; ++sj)
                mreg[ti][sj] = *(const float4*)(mb + (size_t)sj * 16 * S_LEN + ti * 16);
    }
    // stage Q fp32->bf16 into overlay
#pragma unroll
    for (int sw = 0; sw < 16; ++sw) {
        const int row = sw * 8 + rr;
        float4 f = *(const float4*)(qp + (size_t)(s0 + row) * D_DIM + dd);
        uint2 wv; wv.x = pack2(f.x, f.y); wv.y = pack2(f.z, f.w);
        *(uint2*)&Qst[row * LQ + dd] = wv;
    }
    __syncthreads();
    // Q fragments -> registers (B-operand layout for S^T gemm)
    bf16x8 qf[2][4];
#pragma unroll
    for (int sj = 0; sj < 2; ++sj)
#pragma unroll
        for (int kc = 0; kc < 4; ++kc)
            qf[sj][kc] = *(const bf16x8*)&Qst[(32 * w + 16 * sj + l15) * LQ + kc * 32 + qd * 8];
    __syncthreads();
    // write K0/V0 into buf0 (overlay now dead)
#pragma unroll
    for (int sw = 0; sw < 8; ++sw) {
        uint2 wv; wv.x = pack2(kf[sw].x, kf[sw].y); wv.y = pack2(kf[sw].z, kf[sw].w);
        *(uint2*)&smem[(sw * 8 + rr) * LQ + dd] = wv;
    }
#pragma unroll
    for (int i = 0; i < 4; ++i) {
        uint2 wv;
        wv.x = pack2(((const float*)&va[0])[i], ((const float*)&va[1])[i]);
        wv.y = pack2(((const float*)&va[2])[i], ((const float*)&va[3])[i]);
        *(uint2*)&smem[KS_E + (dg + i) * LV + tg] = wv;
        uint2 wv2;
        wv2.x = pack2(((const float*)&vb[0])[i], ((const float*)&vb[1])[i]);
        wv2.y = pack2(((const float*)&vb[2])[i], ((const float*)&vb[3])[i]);
        *(uint2*)&smem[KS_E + (dg + 4 + i) * LV + tg] = wv2;
    }
    __syncthreads();

    f32x4 acc_o[2][8];
#pragma unroll
    for (int i = 0; i < 2; ++i)
#pragma unroll
        for (int j = 0; j < 8; ++j) acc_o[i][j] = (f32x4){0.f, 0.f, 0.f, 0.f};

    // bpermute source addresses (quad exchange), validated in R2
    const int a0 = ((2 * (qd & 1)) * 16 + l15) * 4;
    const int a1 = a0 + 64;
    const bool hi = (qd >= 2);

    int cur = 0;
    for (int it = 0; it < NIT; ++it) {
        const int nxt = cur ^ 1;
        const int tn = (it + 1) * BK;
        const bool pf = (it + 1 < NIT);
        const unsigned short* Ksc = smem + cur * BUF_E;
        const unsigned short* Vtc = smem + cur * BUF_E + KS_E;
        unsigned short* Ksn = smem + nxt * BUF_E;
        unsigned short* Vtn = smem + nxt * BUF_E + KS_E;

        // ---- issue K(i+1) loads (in flight across S-gemm) ----
        if (pf) {
#pragma unroll
            for (int sw = 0; sw < 8; ++sw)
                kf[sw] = *(const float4*)(kp + (size_t)(tn + sw * 8 + rr) * D_DIM + dd);
        }

        // ---- S^T = K·Q^T on buffer cur ----
        f32x4 acc_s[4][2];
#pragma unroll
        for (int i = 0; i < 4; ++i)
#pragma unroll
            for (int j = 0; j < 2; ++j) acc_s[i][j] = (f32x4){0.f, 0.f, 0.f, 0.f};
#pragma unroll
        for (int kc = 0; kc < 4; ++kc) {
            const int ko = kc * 32 + qd * 8;
            bf16x8 af[4];
#pragma unroll
            for (int ti = 0; ti < 4; ++ti)
                af[ti] = *(const bf16x8*)&Ksc[(16 * ti + l15) * LQ + ko];
#pragma unroll
            for (int ti = 0; ti < 4; ++ti)
#pragma unroll
                for (int sj = 0; sj < 2; ++sj)
                    acc_s[ti][sj] = __builtin_amdgcn_mfma_f32_16x16x32_bf16(
                        af[ti], qf[sj][kc], acc_s[ti][sj], 0, 0, 0);
        }

        // ---- drain K(i+1), pack into buffer nxt; then issue V(i+1) loads ----
        if (pf) {
#pragma unroll
            for (int sw = 0; sw < 8; ++sw) {
                uint2 wv; wv.x = pack2(kf[sw].x, kf[sw].y); wv.y = pack2(kf[sw].z, kf[sw].w);
                *(uint2*)&Ksn[(sw * 8 + rr) * LQ + dd] = wv;
            }
#pragma unroll
            for (int r = 0; r < 4; ++r) {
                va[r] = *(const float4*)(vp + (size_t)(tn + tg + r) * D_DIM + dg);
                vb[r] = *(const float4*)(vp + (size_t)(tn + tg + r) * D_DIM + dg + 4);
            }
        }

        // ---- P = S^T ∘ mask -> packed bf16 ----
        int pu[4][2][2];
#pragma unroll
        for (int ti = 0; ti < 4; ++ti)
#pragma unroll
            for (int sj = 0; sj < 2; ++sj) {
                f32x4 sv = acc_s[ti][sj];
                float4 m = mreg[ti][sj];
                pu[ti][sj][0] = (int)pack2(sv[0] * m.x, sv[1] * m.y);
                pu[ti][sj][1] = (int)pack2(sv[2] * m.z, sv[3] * m.w);
            }

        // ---- prefetch mask(i+1): full-iteration latency window ----
        if (pf) {
            const float* mb = mp + (size_t)(s0 + 32 * w + l15) * S_LEN + tn + 4 * qd;
#pragma unroll
            for (int ti = 0; ti < 4; ++ti)
#pragma unroll
                for (int sj = 0; sj < 2; ++sj)
                    mreg[ti][sj] = *(const float4*)(mb + (size_t)sj * 16 * S_LEN + ti * 16);
        }

        // ---- quad-exchange + O += P·V on buffer cur ----
#pragma unroll
        for (int kc2 = 0; kc2 < 2; ++kc2) {
            bf16x8 ap[2];
#pragma unroll
            for (int sj = 0; sj < 2; ++sj) {
                const int tA = 2 * kc2, tB = 2 * kc2 + 1;
                int w0a = __builtin_amdgcn_ds_bpermute(a0, pu[tA][sj][0]);
                int w0b = __builtin_amdgcn_ds_bpermute(a0, pu[tB][sj][0]);
                int w1a = __builtin_amdgcn_ds_bpermute(a0, pu[tA][sj][1]);
                int w1b = __builtin_amdgcn_ds_bpermute(a0, pu[tB][sj][1]);
                int w2a = __builtin_amdgcn_ds_bpermute(a1, pu[tA][sj][0]);
                int w2b = __builtin_amdgcn_ds_bpermute(a1, pu[tB][sj][0]);
                int w3a = __builtin_amdgcn_ds_bpermute(a1, pu[tA][sj][1]);
                int w3b = __builtin_amdgcn_ds_bpermute(a1, pu[tB][sj][1]);
                union { i32x4 i; bf16x8 b; } u;
                u.i = (i32x4){hi ? w0b : w0a, hi ? w1b : w1a,
                              hi ? w2b : w2a, hi ? w3b : w3a};
                ap[sj] = u.b;
            }
            const int ko = kc2 * 32 + qd * 8;
#pragma unroll
            for (int dj = 0; dj < 8; ++dj) {
                bf16x8 bv = *(const bf16x8*)&Vtc[(16 * dj + l15) * LV + ko];
#pragma unroll
                for (int si = 0; si < 2; ++si)
                    acc_o[si][dj] = __builtin_amdgcn_mfma_f32_16x16x32_bf16(
                        ap[si], bv, acc_o[si][dj], 0, 0, 0);
            }
        }

        // ---- drain V(i+1), pack into buffer nxt ----
        if (pf) {
#pragma unroll
            for (int i = 0; i < 4; ++i) {
                uint2 wv;
                wv.x = pack2(((const float*)&va[0])[i], ((const float*)&va[1])[i]);
                wv.y = pack2(((const float*)&va[2])[i], ((const float*)&va[3])[i]);
                *(uint2*)&Vtn[(dg + i) * LV + tg] = wv;
                uint2 wv2;
                wv2.x = pack2(((const float*)&vb[0])[i], ((const float*)&vb[1])[i]);
                wv2.y = pack2(((const float*)&vb[2])[i], ((const float*)&vb[3])[i]);
                *(uint2*)&Vtn[(dg + 4 + i) * LV + tg] = wv2;
            }
        }

        __syncthreads();  // iter i reads of buf cur done; i+1 may overwrite it
        cur = nxt;
    }

    // ---- epilogue: O[s][d], C-layout row=4qd+r, col=l15 ----
#pragma unroll
    for (int si = 0; si < 2; ++si)
#pragma unroll
        for (int dj = 0; dj < 8; ++dj) {
#pragma unroll
            for (int r = 0; r < 4; ++r) {
                const int srow = s0 + 32 * w + 16 * si + 4 * qd + r;
                op[(size_t)srow * D_DIM + 16 * dj + l15] = acc_o[si][dj][r];
            }
        }
}

extern "C" void kernel_launch(void* const* d_in, const int* in_sizes, int n_in,
                              void* d_out, int out_size, void* d_ws, size_t ws_size,
                              hipStream_t stream) {
    const float* q = (const float*)d_in[0];
    const float* k = (const float*)d_in[1];
    const float* v = (const float*)d_in[2];
    const float* m = (const float*)d_in[3];
    float* out = (float*)d_out;
    // 32 heads * 16 q-tiles = 512 blocks; 2 blocks/CU co-resident
    fused_qkmv<<<dim3(512), dim3(256), 0, stream>>>(q, k, v, m, out);
}